// Round 1
// baseline (2994.799 us; speedup 1.0000x reference)
//
#include <hip/hip_runtime.h>

// Problem constants (match reference)
constexpr int   N_POINTS     = 262144;
constexpr int   FEAT_DIM     = 512;
constexpr int   NUM_LABELS   = 200;
constexpr int   NUM_NEG      = 8;
constexpr int   IGNORE_LABEL = 255;
constexpr float NEG_THRESH   = 0.85f;
constexpr float POS_THRESH   = 0.0f;
constexpr float EPS          = 1e-7f;

// d_out layout: out[0] = loss, out[1..N] = pos_loss, out[1+N..1+2N] = neg_loss
// d_ws layout:  ws[0] = sum_pos, ws[1] = sum_neg, ws[2..2+200) = ||anchor||^2

__global__ void zero_ws_kernel(float* ws) {
    ws[0] = 0.f;
    ws[1] = 0.f;
}

// Precompute ||anchor_r||^2 for the 200 anchors: one wave per row.
__global__ __launch_bounds__(256) void a2_kernel(const float* __restrict__ anchors,
                                                 float* __restrict__ a2) {
    const int w    = (blockIdx.x * 256 + threadIdx.x) >> 6;
    const int lane = threadIdx.x & 63;
    if (w >= NUM_LABELS) return;
    const float4* row = (const float4*)(anchors + (size_t)w * FEAT_DIM);
    const float4 a = row[lane];
    const float4 b = row[lane + 64];
    float s = a.x*a.x + a.y*a.y + a.z*a.z + a.w*a.w
            + b.x*b.x + b.y*b.y + b.z*b.z + b.w*b.w;
#pragma unroll
    for (int off = 32; off > 0; off >>= 1) s += __shfl_xor(s, off, 64);
    if (lane == 0) a2[w] = s;
}

// 16 lanes per point (4 points per wave, 16 points per 256-thread block).
// Dot-product form: d2 = f2 - 2*dot + a2  (exactly the reference's expansion).
// Each lane owns 8 float4-chunks of the feature row (qlane + 16*j), so every
// quarter-wave load is a contiguous 256 B segment -> fully coalesced.
__global__ __launch_bounds__(256, 4) void ccl_main_kernel(
    const float* __restrict__ features,   // [N, 512]
    const int*   __restrict__ labels,     // [N]
    const float* __restrict__ anchors,    // [200, 512]
    const int*   __restrict__ neg_inds,   // [N, 8]
    const float* __restrict__ a2,         // [200] precomputed ||a||^2
    float*       __restrict__ out,        // [1 + 2N]
    float*       __restrict__ ws)         // [2] partial sums
{
    const int tid   = threadIdx.x;
    const int qlane = tid & 15;          // lane within 16-lane quarter
    const int quart = tid >> 4;          // point slot in block (0..15)
    const int p     = blockIdx.x * 16 + quart;   // grid sized exactly: no bounds check

    float* pos_out = out + 1;
    float* neg_out = out + 1 + N_POINTS;

    // Quarter-uniform gathers (4 unique addresses per wave instr, L1-friendly).
    const int  lab   = labels[p];
    const bool valid = (lab != IGNORE_LABEL);
    int idx[9];
    idx[0] = valid ? lab : 0;
#pragma unroll
    for (int k = 0; k < NUM_NEG; ++k)
        idx[k + 1] = neg_inds[(size_t)p * NUM_NEG + k];

    const float4* frow = (const float4*)(features + (size_t)p * FEAT_DIM);
    float4 f[8];
#pragma unroll
    for (int j = 0; j < 8; ++j) f[j] = frow[qlane + 16 * j];

    float f2 = 0.f;
#pragma unroll
    for (int j = 0; j < 8; ++j) {
        f2 = fmaf(f[j].x, f[j].x, f2);
        f2 = fmaf(f[j].y, f[j].y, f2);
        f2 = fmaf(f[j].z, f[j].z, f2);
        f2 = fmaf(f[j].w, f[j].w, f2);
    }

    float dot[9];
#pragma unroll
    for (int k = 0; k < 9; ++k) {
        const float4* arow = (const float4*)(anchors + (size_t)idx[k] * FEAT_DIM);
        float s = 0.f;
#pragma unroll
        for (int j = 0; j < 8; ++j) {
            const float4 a = arow[qlane + 16 * j];
            s = fmaf(f[j].x, a.x, s);
            s = fmaf(f[j].y, a.y, s);
            s = fmaf(f[j].z, a.z, s);
            s = fmaf(f[j].w, a.w, s);
        }
        dot[k] = s;
    }

    // Reduce f2 + 9 dots across the 16-lane quarter: 4-step butterfly each.
#pragma unroll
    for (int off = 8; off > 0; off >>= 1) f2 += __shfl_xor(f2, off, 16);
#pragma unroll
    for (int k = 0; k < 9; ++k) {
        float v = dot[k];
#pragma unroll
        for (int off = 8; off > 0; off >>= 1) v += __shfl_xor(v, off, 16);
        dot[k] = v;
    }

    // Epilogue (computed redundantly in all 16 lanes; lane 0 writes).
    const float pos_d2   = f2 - 2.f * dot[0] + a2[idx[0]];
    float       pos_dist = sqrtf(fmaxf(pos_d2, 0.f) + EPS);
    float acc = 0.f;
#pragma unroll
    for (int k = 1; k < 9; ++k) {
        const float d2 = f2 - 2.f * dot[k] + a2[idx[k]];
        acc += sqrtf(fmaxf(d2, 0.f) + EPS);
    }
    float neg_dist = acc * (1.0f / NUM_NEG);

    if (!valid) { pos_dist = 0.f; neg_dist = 0.f; }

    const float pos_loss = fmaxf(pos_dist - POS_THRESH, 0.f);
    const float neg_loss = fmaxf(NEG_THRESH - neg_dist, 0.f);

    __shared__ float sp[16], sn[16];
    if (qlane == 0) {
        pos_out[p] = pos_loss;
        neg_out[p] = neg_loss;
        sp[quart]  = pos_loss;
        sn[quart]  = neg_loss;
    }
    __syncthreads();
    if (tid == 0) {
        float s0 = 0.f, s1 = 0.f;
#pragma unroll
        for (int i = 0; i < 16; ++i) { s0 += sp[i]; s1 += sn[i]; }
        atomicAdd(&ws[0], s0);
        atomicAdd(&ws[1], s1);
    }
}

__global__ void finalize_kernel(const float* __restrict__ ws,
                                float* __restrict__ out) {
    out[0] = (ws[0] + ws[1]) * (1.0f / (float)N_POINTS);
}

extern "C" void kernel_launch(void* const* d_in, const int* in_sizes, int n_in,
                              void* d_out, int out_size, void* d_ws, size_t ws_size,
                              hipStream_t stream) {
    const float* features = (const float*)d_in[0];
    const int*   labels   = (const int*)  d_in[1];
    const float* anchors  = (const float*)d_in[2];
    const int*   neg_inds = (const int*)  d_in[3];
    float* out = (float*)d_out;
    float* ws  = (float*)d_ws;
    float* a2  = ws + 2;   // 200 floats of workspace for anchor norms

    zero_ws_kernel<<<1, 1, 0, stream>>>(ws);

    // 200 waves = 50 blocks of 256 threads
    a2_kernel<<<50, 256, 0, stream>>>(anchors, a2);

    // 16 points per block -> exactly N_POINTS / 16 = 16384 blocks, no tail.
    ccl_main_kernel<<<N_POINTS / 16, 256, 0, stream>>>(features, labels, anchors,
                                                       neg_inds, a2, out, ws);

    finalize_kernel<<<1, 1, 0, stream>>>(ws, out);
}

// Round 2
// 1029.214 us; speedup vs baseline: 2.9098x; 2.9098x over previous
//
#include <hip/hip_runtime.h>

// Problem constants (match reference)
constexpr int   N_POINTS     = 262144;
constexpr int   FEAT_DIM     = 512;
constexpr int   NUM_LABELS   = 200;
constexpr int   NUM_NEG      = 8;
constexpr int   IGNORE_LABEL = 255;
constexpr float NEG_THRESH   = 0.85f;
constexpr float POS_THRESH   = 0.0f;
constexpr float EPS          = 1e-7f;

constexpr int NBLOCKS = 1024;          // 4 blocks/CU, 16 waves/CU
constexpr int PPB     = 16;            // points per block per iteration
constexpr int ITERS   = N_POINTS / (NBLOCKS * PPB);   // = 16, exact

// d_out layout: out[0] = loss, out[1..N] = pos_loss, out[1+N..1+2N] = neg_loss
// d_ws layout:  ws[0] = sum_pos, ws[1] = sum_neg, ws[2..2+200) = ||anchor||^2

__global__ void zero_ws_kernel(float* ws) {
    ws[0] = 0.f;
    ws[1] = 0.f;
}

// Precompute ||anchor_r||^2 for the 200 anchors: one wave per row.
__global__ __launch_bounds__(256) void a2_kernel(const float* __restrict__ anchors,
                                                 float* __restrict__ a2) {
    const int w    = (blockIdx.x * 256 + threadIdx.x) >> 6;
    const int lane = threadIdx.x & 63;
    if (w >= NUM_LABELS) return;
    const float4* row = (const float4*)(anchors + (size_t)w * FEAT_DIM);
    const float4 a = row[lane];
    const float4 b = row[lane + 64];
    float s = a.x*a.x + a.y*a.y + a.z*a.z + a.w*a.w
            + b.x*b.x + b.y*b.y + b.z*b.z + b.w*b.w;
#pragma unroll
    for (int off = 32; off > 0; off >>= 1) s += __shfl_xor(s, off, 64);
    if (lane == 0) a2[w] = s;
}

// 16 lanes per point (4 points/wave, 16 points per 256-thread block),
// grid-stride over 16 iterations. Dot-form d2 = f2 - 2*dot + a2.
// Loop nest is j(chunk)-outer / k(anchor)-inner so each j-step issues a
// BATCH of 10 independent float4 loads (1 feature + 9 anchors) before the
// 40 FMAs that consume them -> L2 latency amortized 10x instead of the
// round-1 one-load-in-flight serialization (VGPR pressure).
__global__ __launch_bounds__(256, 4) void ccl_main_kernel(
    const float* __restrict__ features,   // [N, 512]
    const int*   __restrict__ labels,     // [N]
    const float* __restrict__ anchors,    // [200, 512]
    const int*   __restrict__ neg_inds,   // [N, 8]
    const float* __restrict__ a2,         // [200] precomputed ||a||^2
    float*       __restrict__ out,        // [1 + 2N]
    float*       __restrict__ ws)         // [2] partial sums
{
    const int tid   = threadIdx.x;
    const int qlane = tid & 15;          // lane within 16-lane quarter
    const int quart = tid >> 4;          // point slot in block (0..15)

    float* pos_out = out + 1;
    float* neg_out = out + 1 + N_POINTS;

    float sum_pos = 0.f, sum_neg = 0.f;

    for (int it = 0; it < ITERS; ++it) {
        const int p = (it * NBLOCKS + blockIdx.x) * PPB + quart;

        const int  lab   = labels[p];
        const bool valid = (lab != IGNORE_LABEL);
        int idx[9];
        idx[0] = valid ? lab : 0;
#pragma unroll
        for (int k = 0; k < NUM_NEG; ++k)
            idx[k + 1] = neg_inds[(size_t)p * NUM_NEG + k];

        const float4* frow = (const float4*)(features + (size_t)p * FEAT_DIM);
        const float4* arow[9];
#pragma unroll
        for (int k = 0; k < 9; ++k)
            arow[k] = (const float4*)(anchors + (size_t)idx[k] * FEAT_DIM);

        float f2 = 0.f;
        float dot[9];
#pragma unroll
        for (int k = 0; k < 9; ++k) dot[k] = 0.f;

#pragma unroll
        for (int j = 0; j < 8; ++j) {
            // one batch of 10 independent loads
            const float4 fj = frow[qlane + 16 * j];
            float4 a[9];
#pragma unroll
            for (int k = 0; k < 9; ++k) a[k] = arow[k][qlane + 16 * j];

            f2 = fmaf(fj.x, fj.x, f2);
            f2 = fmaf(fj.y, fj.y, f2);
            f2 = fmaf(fj.z, fj.z, f2);
            f2 = fmaf(fj.w, fj.w, f2);
#pragma unroll
            for (int k = 0; k < 9; ++k) {
                float s = dot[k];
                s = fmaf(fj.x, a[k].x, s);
                s = fmaf(fj.y, a[k].y, s);
                s = fmaf(fj.z, a[k].z, s);
                s = fmaf(fj.w, a[k].w, s);
                dot[k] = s;
            }
        }

        // Reduce f2 + 9 dots across the 16-lane quarter (4-step butterflies).
#pragma unroll
        for (int off = 8; off > 0; off >>= 1) f2 += __shfl_xor(f2, off, 16);
#pragma unroll
        for (int k = 0; k < 9; ++k) {
            float v = dot[k];
#pragma unroll
            for (int off = 8; off > 0; off >>= 1) v += __shfl_xor(v, off, 16);
            dot[k] = v;
        }

        // Epilogue (identical math to the reference's expansion).
        const float pos_d2   = f2 - 2.f * dot[0] + a2[idx[0]];
        float       pos_dist = sqrtf(fmaxf(pos_d2, 0.f) + EPS);
        float acc = 0.f;
#pragma unroll
        for (int k = 1; k < 9; ++k) {
            const float d2 = f2 - 2.f * dot[k] + a2[idx[k]];
            acc += sqrtf(fmaxf(d2, 0.f) + EPS);
        }
        float neg_dist = acc * (1.0f / NUM_NEG);

        if (!valid) { pos_dist = 0.f; neg_dist = 0.f; }

        const float pos_loss = fmaxf(pos_dist - POS_THRESH, 0.f);
        const float neg_loss = fmaxf(NEG_THRESH - neg_dist, 0.f);

        if (qlane == 0) {
            pos_out[p] = pos_loss;
            neg_out[p] = neg_loss;
            sum_pos += pos_loss;
            sum_neg += neg_loss;
        }
    }

    // One atomic pair per block (2048 atomics total across the grid).
    __shared__ float sp[16], sn[16];
    if (qlane == 0) { sp[quart] = sum_pos; sn[quart] = sum_neg; }
    __syncthreads();
    if (tid == 0) {
        float s0 = 0.f, s1 = 0.f;
#pragma unroll
        for (int i = 0; i < 16; ++i) { s0 += sp[i]; s1 += sn[i]; }
        atomicAdd(&ws[0], s0);
        atomicAdd(&ws[1], s1);
    }
}

__global__ void finalize_kernel(const float* __restrict__ ws,
                                float* __restrict__ out) {
    out[0] = (ws[0] + ws[1]) * (1.0f / (float)N_POINTS);
}

extern "C" void kernel_launch(void* const* d_in, const int* in_sizes, int n_in,
                              void* d_out, int out_size, void* d_ws, size_t ws_size,
                              hipStream_t stream) {
    const float* features = (const float*)d_in[0];
    const int*   labels   = (const int*)  d_in[1];
    const float* anchors  = (const float*)d_in[2];
    const int*   neg_inds = (const int*)  d_in[3];
    float* out = (float*)d_out;
    float* ws  = (float*)d_ws;
    float* a2  = ws + 2;   // 200 floats of workspace for anchor norms

    zero_ws_kernel<<<1, 1, 0, stream>>>(ws);

    // 200 waves = 50 blocks of 256 threads
    a2_kernel<<<50, 256, 0, stream>>>(anchors, a2);

    ccl_main_kernel<<<NBLOCKS, 256, 0, stream>>>(features, labels, anchors,
                                                 neg_inds, a2, out, ws);

    finalize_kernel<<<1, 1, 0, stream>>>(ws, out);
}